// Round 1
// 225.560 us; speedup vs baseline: 1.1090x; 1.1090x over previous
//
#include <hip/hip_runtime.h>
#include <stdint.h>

// Problem constants (fixed shapes from reference)
#define M_DIM 4096   // 2 * 2048 rows of x
#define K_DIM 4096   // in_features
#define N_DIM 4096   // out_features

typedef float f32x4 __attribute__((ext_vector_type(4)));
typedef int   i32x4 __attribute__((ext_vector_type(4)));

// ---------------------------------------------------------------------------
// Kernel 1: x fp32 -> i8 with per-row scale. One block per row (4096 rows),
// 256 threads x 16 elems. absmax reduce (shuffle + LDS), round-to-nearest.
// (unchanged from R4 — isolates the GEMM schedule change)
// ---------------------------------------------------------------------------
__global__ __launch_bounds__(256) void quant_x(const float* __restrict__ x,
                                               int8_t* __restrict__ xq,
                                               float* __restrict__ sx) {
    __shared__ float red[4];
    const int row  = blockIdx.x;
    const int base = threadIdx.x * 16;
    const float* xr = x + (size_t)row * K_DIM + base;
    float4 v[4];
#pragma unroll
    for (int c = 0; c < 4; ++c) v[c] = ((const float4*)xr)[c];
    float am = 0.f;
#pragma unroll
    for (int c = 0; c < 4; ++c) {
        am = fmaxf(am, fabsf(v[c].x)); am = fmaxf(am, fabsf(v[c].y));
        am = fmaxf(am, fabsf(v[c].z)); am = fmaxf(am, fabsf(v[c].w));
    }
#pragma unroll
    for (int off = 32; off; off >>= 1) am = fmaxf(am, __shfl_xor(am, off, 64));
    if ((threadIdx.x & 63) == 0) red[threadIdx.x >> 6] = am;
    __syncthreads();
    float amax = fmaxf(fmaxf(red[0], red[1]), fmaxf(red[2], red[3]));
    amax = fmaxf(amax, 1e-20f);
    const float inv = 127.0f / amax;
    int ow[4];
#pragma unroll
    for (int c = 0; c < 4; ++c) {
        int q0 = __float2int_rn(v[c].x * inv);
        int q1 = __float2int_rn(v[c].y * inv);
        int q2 = __float2int_rn(v[c].z * inv);
        int q3 = __float2int_rn(v[c].w * inv);
        ow[c] = (q0 & 255) | ((q1 & 255) << 8) | ((q2 & 255) << 16) | ((q3 & 255) << 24);
    }
    ((int4*)(xq + (size_t)row * K_DIM + base))[0] = make_int4(ow[0], ow[1], ow[2], ow[3]);
    if (threadIdx.x == 0) sx[row] = amax / 127.0f;
}

// ---------------------------------------------------------------------------
// Kernel 2: Q4_K dequant -> i8 W with per-row scale. (unchanged from R4)
// ---------------------------------------------------------------------------
__global__ __launch_bounds__(256) void quant_w(const int* __restrict__ packed,
                                               const float* __restrict__ d,
                                               const float* __restrict__ dmin,
                                               const int* __restrict__ scales,
                                               const int* __restrict__ mins,
                                               int8_t* __restrict__ wq,
                                               float* __restrict__ sw) {
    __shared__ float sa[128], sb[128], red[4];
    const int n = blockIdx.x;
    const int t = threadIdx.x;
    float m = 0.f;
    if (t < 128) {
        int sub  = n * 128 + t;
        int sidx = n * 16 + (t >> 3);
        float dd = d[sidx], dm = dmin[sidx];
        float a = dd * (float)scales[sub] * (1.0f / 945.0f);
        float b = dd * (float)mins[sub] * (1.0f / 63.0f) + dm;
        sa[t] = a; sb[t] = b;
        m = 15.0f * a + b;
    }
#pragma unroll
    for (int off = 32; off; off >>= 1) m = fmaxf(m, __shfl_xor(m, off, 64));
    if ((t & 63) == 0) red[t >> 6] = m;
    __syncthreads();
    float rowmax = fmaxf(fmaxf(red[0], red[1]), fmaxf(red[2], red[3]));
    rowmax = fmaxf(rowmax, 1e-20f);
    const float inv = 127.0f / rowmax;

    const int sub = t >> 1;                    // 16 weights = half a subblock
    const float a = sa[sub] * inv;
    const float b = sb[sub] * inv;
    const int4* p4 = (const int4*)(packed + (size_t)n * (K_DIM / 2) + t * 8);
    int4 pv0 = p4[0], pv1 = p4[1];
    int bytes[8] = {pv0.x, pv0.y, pv0.z, pv0.w, pv1.x, pv1.y, pv1.z, pv1.w};
    int ow[4];
#pragma unroll
    for (int c = 0; c < 4; ++c) {
        int b0 = bytes[2 * c], b1 = bytes[2 * c + 1];
        int q0 = __float2int_rn((float)(b0 & 15) * a + b);
        int q1 = __float2int_rn((float)((b0 >> 4) & 15) * a + b);
        int q2 = __float2int_rn((float)(b1 & 15) * a + b);
        int q3 = __float2int_rn((float)((b1 >> 4) & 15) * a + b);
        ow[c] = (q0 & 255) | ((q1 & 255) << 8) | ((q2 & 255) << 16) | ((q3 & 255) << 24);
    }
    ((int4*)(wq + (size_t)n * K_DIM + t * 16))[0] = make_int4(ow[0], ow[1], ow[2], ow[3]);
    if (t == 0) sw[n] = rowmax / 127.0f;
}

// ---------------------------------------------------------------------------
// Kernel 3: C[M,N](fp32) = sx[m]*sw[n] * (Aq . Bq^T), i8 MFMA 16x16x64.
// 256x256 tile, BK=128 B, 512 thr / 8 waves (2M x 4N), 128 KiB LDS.
// 8-phase schedule (T3+T4+T5): per phase { ds_reads | 1 half-tile stage |
// barrier | lgkmcnt(0) | setprio(1) 16 MFMA setprio(0) | barrier }, counted
// vmcnt(4) ONLY at phases 4 and 8 (never 0 in the main loop).
//
// Halves: A0/A1 = tile rows 0-127 / 128-255; B0/B1 = tile cols 0-127/128-255.
// Wave (wm,wn) owns rows {a*128 + wm*64 + 0..63} x cols {b*128 + wn*32+0..31}
// for a,b in {0,1} -> quadrant Q(a,b) = 4x2 frags x 2 ksteps = 16 MFMA.
// Per-iteration (t even; tile t in buf0, t+1 in buf1):
//   compute P1:Q00(t) P2:Q01(t) P3:Q11(t) P4:Q10(t)  then same for t+1
//   stage   P1:A1(t+1) P2:B0(t+1) P3:A0(t+2) P4:B1(t+2)
//           P5:A1(t+2) P6:B0(t+2) P7:A0(t+3) P8:B1(t+3)
// Verified: every stage lands >=1 phase after its region's last ds_read, and
// vmcnt(4)@P4/P8 guarantees each half arrives before its first ds_read
// (2 halves = 4 loads stay in flight across every checkpoint).
//
// LDS layout (per buf/half, 128 rows x 128 B): logical 16B chunk c of row r
// stored at slot c ^ (r&7) (involution; same XOR on stage-source and read ->
// rule #21 satisfied). ds_read_b128: per quarter-wave 2 lanes/bank-quad =
// free (m136).
// ---------------------------------------------------------------------------
#define BK 128   // bytes of K per K-tile (2 MFMA k-steps of 64)

__device__ __forceinline__ void async_copy16(void* lds, const void* g) {
    __builtin_amdgcn_global_load_lds(
        (const __attribute__((address_space(1))) void*)g,
        (__attribute__((address_space(3))) void*)lds, 16, 0, 0);
}

#define BARRIER() asm volatile("s_barrier" ::: "memory")
#define LGKM0()   asm volatile("s_waitcnt lgkmcnt(0)" ::: "memory")
#define WAITV(n)  asm volatile("s_waitcnt vmcnt(" #n ")" ::: "memory")

__global__ __launch_bounds__(512, 2) void gemm_i8(const int8_t* __restrict__ A,
                                                  const int8_t* __restrict__ B,
                                                  const float* __restrict__ sx,
                                                  const float* __restrict__ sw,
                                                  float* __restrict__ C) {
    // [buf][half][128 rows * 128 B] — 2*2*16 KB per matrix = 128 KiB total
    __shared__ int8_t sA[2][2][128 * 128];
    __shared__ int8_t sB[2][2][128 * 128];

    const int tid  = threadIdx.x;
    const int wave = tid >> 6;
    const int lane = tid & 63;
    const int wm = wave >> 2;       // 0..1
    const int wn = wave & 3;        // 0..3
    const int r4 = lane & 15;
    const int q  = lane >> 4;

    // XCD-aware bijective swizzle: 256 blocks = 8 XCDs x 32 contiguous tiles
    const int bid = blockIdx.x;
    const int lid = (bid & 7) * 32 + (bid >> 3);
    const int m0 = (lid & 15) * 256;
    const int n0 = (lid >> 4) * 256;

    i32x4 acc[2][2][4][2] = {};     // [a][b][m][n] -> 128 VGPRs
    i32x4 aF[2][4], bF[2][2];       // [kstep][frag]

    // ---- staging map: load l in {0,1}: physical chunk p = l*512 + tid ----
    // row = p>>3 (0..127), slot = p&7, logical chunk c = slot ^ (row&7).
    // (row1&7 == row0&7, so c is the same for both loads.)
    const int rowS = tid >> 3;                       // l=0 rows 0..63
    const int cS   = (tid & 7) ^ (rowS & 7);
    const size_t rs64 = (size_t)64 * K_DIM;          // l=1 is +64 rows
    const int8_t* gAh[2];
    const int8_t* gBh[2];
    gAh[0] = A + (size_t)(m0 + rowS) * K_DIM + cS * 16;
    gAh[1] = gAh[0] + (size_t)128 * K_DIM;
    gBh[0] = B + (size_t)(n0 + rowS) * K_DIM + cS * 16;
    gBh[1] = gBh[0] + (size_t)128 * K_DIM;
    // LDS dest is wave-uniform base + lane*16 (HW adds lane offset)
    const int ldsW = wave * 1024;

#define STAGE_A(buf, half, koff)                                          \
    do {                                                                  \
        async_copy16(&sA[buf][half][ldsW],        gAh[half] + (koff));    \
        async_copy16(&sA[buf][half][ldsW + 8192], gAh[half] + rs64 + (koff)); \
    } while (0)
#define STAGE_B(buf, half, koff)                                          \
    do {                                                                  \
        async_copy16(&sB[buf][half][ldsW],        gBh[half] + (koff));    \
        async_copy16(&sB[buf][half][ldsW + 8192], gBh[half] + rs64 + (koff)); \
    } while (0)

    // ---- fragment LDS offsets (per-thread constants) ----
    // A frag (m,ks): row = wm*64 + m*16 + r4, slot = (ks*4+q) ^ (r4&7)
    // B frag (n,ks): row = wn*32 + n*16 + r4, same slot XOR
    int aOff[2][4], bOff[2][2];
#pragma unroll
    for (int ks = 0; ks < 2; ++ks) {
        const int sl = (((ks * 4 + q) ^ (r4 & 7)) * 16);
#pragma unroll
        for (int m = 0; m < 4; ++m)
            aOff[ks][m] = (wm * 64 + m * 16 + r4) * 128 + sl;
#pragma unroll
        for (int n = 0; n < 2; ++n)
            bOff[ks][n] = (wn * 32 + n * 16 + r4) * 128 + sl;
    }

#define LDA(buf, half)                                                    \
    do {                                                                  \
        _Pragma("unroll") for (int ks = 0; ks < 2; ++ks)                  \
        _Pragma("unroll") for (int m = 0; m < 4; ++m)                     \
            aF[ks][m] = *(const i32x4*)&sA[buf][half][aOff[ks][m]];       \
    } while (0)
#define LDB(buf, half)                                                    \
    do {                                                                  \
        _Pragma("unroll") for (int ks = 0; ks < 2; ++ks)                  \
        _Pragma("unroll") for (int n = 0; n < 2; ++n)                     \
            bF[ks][n] = *(const i32x4*)&sB[buf][half][bOff[ks][n]];       \
    } while (0)
#define MMA(a, b)                                                         \
    do {                                                                  \
        __builtin_amdgcn_s_setprio(1);                                    \
        _Pragma("unroll") for (int m = 0; m < 4; ++m)                     \
        _Pragma("unroll") for (int n = 0; n < 2; ++n) {                   \
            acc[a][b][m][n] = __builtin_amdgcn_mfma_i32_16x16x64_i8(      \
                aF[0][m], bF[0][n], acc[a][b][m][n], 0, 0, 0);            \
            acc[a][b][m][n] = __builtin_amdgcn_mfma_i32_16x16x64_i8(      \
                aF[1][m], bF[1][n], acc[a][b][m][n], 0, 0, 0);            \
        }                                                                 \
        __builtin_amdgcn_s_setprio(0);                                    \
    } while (0)

    // ---- prologue: tile 0 fully + A0(1), B1(1); first 4 halves must land --
    STAGE_A(0, 0, 0);        // A0(0)
    STAGE_B(0, 0, 0);        // B0(0)
    STAGE_B(0, 1, 0);        // B1(0)
    STAGE_A(0, 1, 0);        // A1(0)
    STAGE_A(1, 0, BK);       // A0(1)
    STAGE_B(1, 1, BK);       // B1(1)
    WAITV(4);                // tile-0 halves arrived; A0(1),B1(1) in flight
    BARRIER();

    int ko1 = BK, ko2 = 2 * BK, ko3 = 3 * BK;
#pragma unroll 1
    for (int it = 0; it < 15; ++it) {          // tiles t=2*it, t+1 of 32
        // P1
        LDA(0, 0); LDB(0, 0); STAGE_A(1, 1, ko1);
        BARRIER(); LGKM0(); MMA(0, 0); BARRIER();
        // P2
        LDB(0, 1); STAGE_B(1, 0, ko1);
        BARRIER(); LGKM0(); MMA(0, 1); BARRIER();
        // P3
        LDA(0, 1); STAGE_A(0, 0, ko2);
        BARRIER(); LGKM0(); MMA(1, 1); BARRIER();
        // P4  (checkpoint: everything through B0(t+1) arrived)
        LDB(0, 0); STAGE_B(0, 1, ko2); WAITV(4);
        BARRIER(); LGKM0(); MMA(1, 0); BARRIER();
        // P5
        LDA(1, 0); LDB(1, 0); STAGE_A(0, 1, ko2);
        BARRIER(); LGKM0(); MMA(0, 0); BARRIER();
        // P6
        LDB(1, 1); STAGE_B(0, 0, ko2);
        BARRIER(); LGKM0(); MMA(0, 1); BARRIER();
        // P7
        LDA(1, 1); STAGE_A(1, 0, ko3);
        BARRIER(); LGKM0(); MMA(1, 1); BARRIER();
        // P8  (checkpoint: everything through B0(t+2) arrived)
        LDB(1, 0); STAGE_B(1, 1, ko3); WAITV(4);
        BARRIER(); LGKM0(); MMA(1, 0); BARRIER();
        ko1 += 2 * BK; ko2 += 2 * BK; ko3 += 2 * BK;
    }

    // ---- epilogue iteration: t = 30, finish staging tile 31, drain ----
    LDA(0, 0); LDB(0, 0); STAGE_A(1, 1, ko1);
    BARRIER(); LGKM0(); MMA(0, 0); BARRIER();
    LDB(0, 1); STAGE_B(1, 0, ko1);
    BARRIER(); LGKM0(); MMA(0, 1); BARRIER();
    LDA(0, 1);
    BARRIER(); LGKM0(); MMA(1, 1); BARRIER();
    LDB(0, 0); WAITV(0);
    BARRIER(); LGKM0(); MMA(1, 0); BARRIER();
    LDA(1, 0); LDB(1, 0);
    BARRIER(); LGKM0(); MMA(0, 0); BARRIER();
    LDB(1, 1);
    BARRIER(); LGKM0(); MMA(0, 1); BARRIER();
    LDA(1, 1);
    BARRIER(); LGKM0(); MMA(1, 1); BARRIER();
    LDB(1, 0);
    BARRIER(); LGKM0(); MMA(1, 0);

    // ---- C write: C/D layout col = lane&15, row = (lane>>4)*4 + reg ----
#pragma unroll
    for (int a = 0; a < 2; ++a)
#pragma unroll
    for (int m = 0; m < 4; ++m) {
        const int rbase = m0 + a * 128 + wm * 64 + m * 16 + q * 4;
        const float4 s4 = *(const float4*)&sx[rbase];
#pragma unroll
        for (int b = 0; b < 2; ++b)
#pragma unroll
        for (int n = 0; n < 2; ++n) {
            const int col = n0 + b * 128 + wn * 32 + n * 16 + r4;
            const float swc = sw[col];
            float* cp = C + (size_t)rbase * N_DIM + col;
            cp[0 * N_DIM] = (float)acc[a][b][m][n][0] * s4.x * swc;
            cp[1 * N_DIM] = (float)acc[a][b][m][n][1] * s4.y * swc;
            cp[2 * N_DIM] = (float)acc[a][b][m][n][2] * s4.z * swc;
            cp[3 * N_DIM] = (float)acc[a][b][m][n][3] * s4.w * swc;
        }
    }
#undef STAGE_A
#undef STAGE_B
#undef LDA
#undef LDB
#undef MMA
}

// ---------------------------------------------------------------------------
// Launch: ws usage = 16.7 MB xq + 16.7 MB wq + 32 KB scales.
// ---------------------------------------------------------------------------
extern "C" void kernel_launch(void* const* d_in, const int* in_sizes, int n_in,
                              void* d_out, int out_size, void* d_ws, size_t ws_size,
                              hipStream_t stream) {
    const float* x      = (const float*)d_in[0];
    const int*   packed = (const int*)d_in[1];
    const float* d      = (const float*)d_in[2];
    const float* dmin   = (const float*)d_in[3];
    const int*   scales = (const int*)d_in[4];
    const int*   mins   = (const int*)d_in[5];
    float* out = (float*)d_out;

    int8_t* xq = (int8_t*)d_ws;                               // 16.7 MB
    int8_t* wq = xq + (size_t)M_DIM * K_DIM;                  // 16.7 MB
    float*  sx = (float*)(wq + (size_t)N_DIM * K_DIM);        // 16 KB
    float*  sw = sx + M_DIM;                                  // 16 KB

    quant_x<<<M_DIM, 256, 0, stream>>>(x, xq, sx);
    quant_w<<<N_DIM, 256, 0, stream>>>(packed, d, dmin, scales, mins, wq, sw);
    gemm_i8<<<256, 512, 0, stream>>>(xq, wq, sx, sw, out);
}

// Round 2
// 220.050 us; speedup vs baseline: 1.1368x; 1.0250x over previous
//
#include <hip/hip_runtime.h>
#include <stdint.h>

// Problem constants (fixed shapes from reference)
#define M_DIM 4096   // 2 * 2048 rows of x
#define K_DIM 4096   // in_features
#define N_DIM 4096   // out_features

typedef float f32x4 __attribute__((ext_vector_type(4)));
typedef int   i32x4 __attribute__((ext_vector_type(4)));

// ---------------------------------------------------------------------------
// Kernel 1: x fp32 -> i8 with per-row scale. (unchanged)
// ---------------------------------------------------------------------------
__global__ __launch_bounds__(256) void quant_x(const float* __restrict__ x,
                                               int8_t* __restrict__ xq,
                                               float* __restrict__ sx) {
    __shared__ float red[4];
    const int row  = blockIdx.x;
    const int base = threadIdx.x * 16;
    const float* xr = x + (size_t)row * K_DIM + base;
    float4 v[4];
#pragma unroll
    for (int c = 0; c < 4; ++c) v[c] = ((const float4*)xr)[c];
    float am = 0.f;
#pragma unroll
    for (int c = 0; c < 4; ++c) {
        am = fmaxf(am, fabsf(v[c].x)); am = fmaxf(am, fabsf(v[c].y));
        am = fmaxf(am, fabsf(v[c].z)); am = fmaxf(am, fabsf(v[c].w));
    }
#pragma unroll
    for (int off = 32; off; off >>= 1) am = fmaxf(am, __shfl_xor(am, off, 64));
    if ((threadIdx.x & 63) == 0) red[threadIdx.x >> 6] = am;
    __syncthreads();
    float amax = fmaxf(fmaxf(red[0], red[1]), fmaxf(red[2], red[3]));
    amax = fmaxf(amax, 1e-20f);
    const float inv = 127.0f / amax;
    int ow[4];
#pragma unroll
    for (int c = 0; c < 4; ++c) {
        int q0 = __float2int_rn(v[c].x * inv);
        int q1 = __float2int_rn(v[c].y * inv);
        int q2 = __float2int_rn(v[c].z * inv);
        int q3 = __float2int_rn(v[c].w * inv);
        ow[c] = (q0 & 255) | ((q1 & 255) << 8) | ((q2 & 255) << 16) | ((q3 & 255) << 24);
    }
    ((int4*)(xq + (size_t)row * K_DIM + base))[0] = make_int4(ow[0], ow[1], ow[2], ow[3]);
    if (threadIdx.x == 0) sx[row] = amax / 127.0f;
}

// ---------------------------------------------------------------------------
// Kernel 2: Q4_K dequant -> i8 W with per-row scale. (unchanged)
// ---------------------------------------------------------------------------
__global__ __launch_bounds__(256) void quant_w(const int* __restrict__ packed,
                                               const float* __restrict__ d,
                                               const float* __restrict__ dmin,
                                               const int* __restrict__ scales,
                                               const int* __restrict__ mins,
                                               int8_t* __restrict__ wq,
                                               float* __restrict__ sw) {
    __shared__ float sa[128], sb[128], red[4];
    const int n = blockIdx.x;
    const int t = threadIdx.x;
    float m = 0.f;
    if (t < 128) {
        int sub  = n * 128 + t;
        int sidx = n * 16 + (t >> 3);
        float dd = d[sidx], dm = dmin[sidx];
        float a = dd * (float)scales[sub] * (1.0f / 945.0f);
        float b = dd * (float)mins[sub] * (1.0f / 63.0f) + dm;
        sa[t] = a; sb[t] = b;
        m = 15.0f * a + b;
    }
#pragma unroll
    for (int off = 32; off; off >>= 1) m = fmaxf(m, __shfl_xor(m, off, 64));
    if ((t & 63) == 0) red[t >> 6] = m;
    __syncthreads();
    float rowmax = fmaxf(fmaxf(red[0], red[1]), fmaxf(red[2], red[3]));
    rowmax = fmaxf(rowmax, 1e-20f);
    const float inv = 127.0f / rowmax;

    const int sub = t >> 1;                    // 16 weights = half a subblock
    const float a = sa[sub] * inv;
    const float b = sb[sub] * inv;
    const int4* p4 = (const int4*)(packed + (size_t)n * (K_DIM / 2) + t * 8);
    int4 pv0 = p4[0], pv1 = p4[1];
    int bytes[8] = {pv0.x, pv0.y, pv0.z, pv0.w, pv1.x, pv1.y, pv1.z, pv1.w};
    int ow[4];
#pragma unroll
    for (int c = 0; c < 4; ++c) {
        int b0 = bytes[2 * c], b1 = bytes[2 * c + 1];
        int q0 = __float2int_rn((float)(b0 & 15) * a + b);
        int q1 = __float2int_rn((float)((b0 >> 4) & 15) * a + b);
        int q2 = __float2int_rn((float)(b1 & 15) * a + b);
        int q3 = __float2int_rn((float)((b1 >> 4) & 15) * a + b);
        ow[c] = (q0 & 255) | ((q1 & 255) << 8) | ((q2 & 255) << 16) | ((q3 & 255) << 24);
    }
    ((int4*)(wq + (size_t)n * K_DIM + t * 16))[0] = make_int4(ow[0], ow[1], ow[2], ow[3]);
    if (t == 0) sw[n] = rowmax / 127.0f;
}

// ---------------------------------------------------------------------------
// Kernel 3: C[M,N](fp32) = sx[m]*sw[n] * (Aq . Bq^T), i8 MFMA 16x16x64.
// 256x256 tile, BK=128 B, 512 thr / 8 waves (2M x 4N), 128 KiB LDS.
//
// R2 change: PREFETCHED-FRAGMENT schedule. R1's phase body was
// {reads; bar; lgkm0; MMA; bar} -> reads execute into an empty matrix pipe
// (zero MFMA/LDS overlap; measured 1540 cy/phase = 653 MFMA + 672 LDS + sync).
// Now each phase's fragments were ds_read during the PREVIOUS phase's MFMA
// issue window: phase = {[WAITV(2) @P4/P8]; STAGE; MFMA x16 (A-prefetch woven
// per-m-block into freed aF regs); B-prefetch; ONE barrier}. No asm lgkmcnt:
// fragment loads are compiler-visible dataflow (compiler emits counted
// lgkmcnt; avoids the MFMA-hoist-past-asm-wait hazard).
//
// Fragment flow per iter (tiles t=2i in buf0, t+1 in buf1):
//   P1 MMA Q00(t)   [aF=A0(t)<-prevP8, bF=B0(t)<-prevP8] stage A1(t+1); PF B1(t)
//   P2 MMA Q01(t)   weave aF<-A1(t);                     stage B0(t+1)
//   P3 MMA Q11(t)   PF bF<-B0(t) (re-read);              stage A0(t+2)
//   P4 WAITV(2); MMA Q10(t) weave aF<-A0(t+1); PF bF<-B0(t+1); stage B1(t+2)
//   P5..P8: same pattern on tile t+1 (stages A1(t+2),B0(t+2),A0(t+3),B1(t+3))
// WAITV(2) at P4/P8 tops retires all stages through 2 phases prior (in-order
// vmem retire, 2 loads/stage) -- exactly covering every prefetched region's
// arrival. Every stage overwrites a region whose last reader completed >=2
// barriers earlier (desk-checked for all 8 stages).
// ---------------------------------------------------------------------------
#define BK 128   // bytes of K per K-tile (2 MFMA k-steps of 64)

__device__ __forceinline__ void async_copy16(void* lds, const void* g) {
    __builtin_amdgcn_global_load_lds(
        (const __attribute__((address_space(1))) void*)g,
        (__attribute__((address_space(3))) void*)lds, 16, 0, 0);
}

#define BARRIER() asm volatile("s_barrier" ::: "memory")
#define WAITV(n)  asm volatile("s_waitcnt vmcnt(" #n ")" ::: "memory")

__global__ __launch_bounds__(512, 2) void gemm_i8(const int8_t* __restrict__ A,
                                                  const int8_t* __restrict__ B,
                                                  const float* __restrict__ sx,
                                                  const float* __restrict__ sw,
                                                  float* __restrict__ C) {
    // [buf][half][128 rows * 128 B] — 2*2*16 KB per matrix = 128 KiB total
    __shared__ int8_t sA[2][2][128 * 128];
    __shared__ int8_t sB[2][2][128 * 128];

    const int tid  = threadIdx.x;
    const int wave = tid >> 6;
    const int lane = tid & 63;
    const int wm = wave >> 2;       // 0..1
    const int wn = wave & 3;        // 0..3
    const int r4 = lane & 15;
    const int q  = lane >> 4;

    // XCD-aware bijective swizzle: 256 blocks = 8 XCDs x 32 contiguous tiles
    const int bid = blockIdx.x;
    const int lid = (bid & 7) * 32 + (bid >> 3);
    const int m0 = (lid & 15) * 256;
    const int n0 = (lid >> 4) * 256;

    i32x4 acc[2][2][4][2] = {};     // [a][b][m][n] -> 128 regs
    i32x4 aF[2][4], bF[2][2];       // [kstep][frag]

    // ---- staging map: load l in {0,1}: physical chunk p = l*512 + tid ----
    // row = p>>3 (0..127), slot = p&7, logical chunk c = slot ^ (row&7).
    const int rowS = tid >> 3;                       // l=0 rows 0..63
    const int cS   = (tid & 7) ^ (rowS & 7);
    const size_t rs64 = (size_t)64 * K_DIM;          // l=1 is +64 rows
    const int8_t* gAh[2];
    const int8_t* gBh[2];
    gAh[0] = A + (size_t)(m0 + rowS) * K_DIM + cS * 16;
    gAh[1] = gAh[0] + (size_t)128 * K_DIM;
    gBh[0] = B + (size_t)(n0 + rowS) * K_DIM + cS * 16;
    gBh[1] = gBh[0] + (size_t)128 * K_DIM;
    // LDS dest is wave-uniform base + lane*16 (HW adds lane offset)
    const int ldsW = wave * 1024;

#define STAGE_A(buf, half, koff)                                          \
    do {                                                                  \
        async_copy16(&sA[buf][half][ldsW],        gAh[half] + (koff));    \
        async_copy16(&sA[buf][half][ldsW + 8192], gAh[half] + rs64 + (koff)); \
    } while (0)
#define STAGE_B(buf, half, koff)                                          \
    do {                                                                  \
        async_copy16(&sB[buf][half][ldsW],        gBh[half] + (koff));    \
        async_copy16(&sB[buf][half][ldsW + 8192], gBh[half] + rs64 + (koff)); \
    } while (0)

    // ---- fragment LDS offsets (per-thread constants) ----
    // A frag (m,ks): row = wm*64 + m*16 + r4, slot = (ks*4+q) ^ (r4&7)
    // B frag (n,ks): row = wn*32 + n*16 + r4, same slot XOR
    int aOff[2][4], bOff[2][2];
#pragma unroll
    for (int ks = 0; ks < 2; ++ks) {
        const int sl = (((ks * 4 + q) ^ (r4 & 7)) * 16);
#pragma unroll
        for (int m = 0; m < 4; ++m)
            aOff[ks][m] = (wm * 64 + m * 16 + r4) * 128 + sl;
#pragma unroll
        for (int n = 0; n < 2; ++n)
            bOff[ks][n] = (wn * 32 + n * 16 + r4) * 128 + sl;
    }

#define LDA(buf, half)                                                    \
    do {                                                                  \
        _Pragma("unroll") for (int ks = 0; ks < 2; ++ks)                  \
        _Pragma("unroll") for (int m = 0; m < 4; ++m)                     \
            aF[ks][m] = *(const i32x4*)&sA[buf][half][aOff[ks][m]];       \
    } while (0)
#define LDB(buf, half)                                                    \
    do {                                                                  \
        _Pragma("unroll") for (int ks = 0; ks < 2; ++ks)                  \
        _Pragma("unroll") for (int n = 0; n < 2; ++n)                     \
            bF[ks][n] = *(const i32x4*)&sB[buf][half][bOff[ks][n]];       \
    } while (0)

// MFMA quadrant, no weave
#define MMA_Q(a, b)                                                       \
    do {                                                                  \
        __builtin_amdgcn_s_setprio(1);                                    \
        _Pragma("unroll") for (int m = 0; m < 4; ++m)                     \
        _Pragma("unroll") for (int n = 0; n < 2; ++n) {                   \
            acc[a][b][m][n] = __builtin_amdgcn_mfma_i32_16x16x64_i8(      \
                aF[0][m], bF[0][n], acc[a][b][m][n], 0, 0, 0);            \
            acc[a][b][m][n] = __builtin_amdgcn_mfma_i32_16x16x64_i8(      \
                aF[1][m], bF[1][n], acc[a][b][m][n], 0, 0, 0);            \
        }                                                                 \
        __builtin_amdgcn_s_setprio(0);                                    \
    } while (0)

// MFMA quadrant with A-prefetch woven per m-block: aF[*][m] reloaded from
// (pbuf,phalf) right after its last consumer in this phase (WAR; backend
// inserts the required hazard handling).
#define MMA_PFA(a, b, pbuf, phalf)                                        \
    do {                                                                  \
        __builtin_amdgcn_s_setprio(1);                                    \
        _Pragma("unroll") for (int m = 0; m < 4; ++m) {                   \
            _Pragma("unroll") for (int n = 0; n < 2; ++n) {               \
                acc[a][b][m][n] = __builtin_amdgcn_mfma_i32_16x16x64_i8(  \
                    aF[0][m], bF[0][n], acc[a][b][m][n], 0, 0, 0);        \
                acc[a][b][m][n] = __builtin_amdgcn_mfma_i32_16x16x64_i8(  \
                    aF[1][m], bF[1][n], acc[a][b][m][n], 0, 0, 0);        \
            }                                                             \
            aF[0][m] = *(const i32x4*)&sA[pbuf][phalf][aOff[0][m]];       \
            aF[1][m] = *(const i32x4*)&sA[pbuf][phalf][aOff[1][m]];       \
        }                                                                 \
        __builtin_amdgcn_s_setprio(0);                                    \
    } while (0)

    // ---- prologue: tile 0 all halves + A0(1), B1(1); preload frags ----
    STAGE_A(0, 0, 0);        // A0(0)
    STAGE_B(0, 0, 0);        // B0(0)
    STAGE_B(0, 1, 0);        // B1(0)
    STAGE_A(0, 1, 0);        // A1(0)
    STAGE_A(1, 0, BK);       // A0(1)   (acts as "prev-P7" stage)
    STAGE_B(1, 1, BK);       // B1(1)   (acts as "prev-P8" stage)
    WAITV(4);                // tile-0 halves arrived; A0(1),B1(1) in flight
    BARRIER();
    LDA(0, 0);               // aF <- A0(0)
    LDB(0, 0);               // bF <- B0(0)

    int ko1 = BK, ko2 = 2 * BK, ko3 = 3 * BK;
#pragma unroll 1
    for (int i = 0; i < 15; ++i) {          // tiles t=2i, t+1 of 32
        // P1: Q00(t); stage A1(t+1); PF bF<-B1(t)
        STAGE_A(1, 1, ko1);
        MMA_Q(0, 0);
        LDB(0, 1);
        BARRIER();
        // P2: Q01(t), weave aF<-A1(t); stage B0(t+1)
        STAGE_B(1, 0, ko1);
        MMA_PFA(0, 1, 0, 1);
        BARRIER();
        // P3: Q11(t); stage A0(t+2); PF bF<-B0(t) (re-read for Q10)
        STAGE_A(0, 0, ko2);
        MMA_Q(1, 1);
        LDB(0, 0);
        BARRIER();
        // P4: checkpoint (covers stages through P2 => A0(t+1), B0(t+1) ready)
        WAITV(2);
        STAGE_B(0, 1, ko2);
        MMA_PFA(1, 0, 1, 0);                // Q10(t), weave aF<-A0(t+1)
        LDB(1, 0);                          // PF bF<-B0(t+1)
        BARRIER();
        // P5: Q00(t+1); stage A1(t+2); PF bF<-B1(t+1)
        STAGE_A(0, 1, ko2);
        MMA_Q(0, 0);
        LDB(1, 1);
        BARRIER();
        // P6: Q01(t+1), weave aF<-A1(t+1); stage B0(t+2)
        STAGE_B(0, 0, ko2);
        MMA_PFA(0, 1, 1, 1);
        BARRIER();
        // P7: Q11(t+1); stage A0(t+3); PF bF<-B0(t+1) (re-read)
        STAGE_A(1, 0, ko3);
        MMA_Q(1, 1);
        LDB(1, 0);
        BARRIER();
        // P8: checkpoint (covers stages through P6 => A0(t+2), B0(t+2) ready)
        WAITV(2);
        STAGE_B(1, 1, ko3);
        MMA_PFA(1, 0, 0, 0);                // Q10(t+1), weave aF<-A0(t+2)
        LDB(0, 0);                          // PF bF<-B0(t+2)
        BARRIER();
        ko1 += 2 * BK; ko2 += 2 * BK; ko3 += 2 * BK;
    }

    // ---- epilogue iter: t=30,31; stage only A1(31),B0(31); drain ----
    STAGE_A(1, 1, ko1);
    MMA_Q(0, 0);
    LDB(0, 1);
    BARRIER();
    STAGE_B(1, 0, ko1);
    MMA_PFA(0, 1, 0, 1);
    BARRIER();
    MMA_Q(1, 1);
    LDB(0, 0);
    BARRIER();
    WAITV(0);                               // A0(31), B0(31) arrived
    MMA_PFA(1, 0, 1, 0);                    // Q10(30), weave aF<-A0(31)
    LDB(1, 0);                              // bF<-B0(31)
    BARRIER();
    MMA_Q(0, 0);                            // Q00(31)
    LDB(1, 1);                              // bF<-B1(31)
    BARRIER();
    MMA_PFA(0, 1, 1, 1);                    // Q01(31), weave aF<-A1(31)
    BARRIER();
    MMA_Q(1, 1);                            // Q11(31)
    LDB(1, 0);                              // bF<-B0(31)
    BARRIER();
    MMA_Q(1, 0);                            // Q10(31)

    // ---- C write: C/D layout col = lane&15, row = (lane>>4)*4 + reg ----
#pragma unroll
    for (int a = 0; a < 2; ++a)
#pragma unroll
    for (int m = 0; m < 4; ++m) {
        const int rbase = m0 + a * 128 + wm * 64 + m * 16 + q * 4;
        const float4 s4 = *(const float4*)&sx[rbase];
#pragma unroll
        for (int b = 0; b < 2; ++b)
#pragma unroll
        for (int n = 0; n < 2; ++n) {
            const int col = n0 + b * 128 + wn * 32 + n * 16 + r4;
            const float swc = sw[col];
            float* cp = C + (size_t)rbase * N_DIM + col;
            cp[0 * N_DIM] = (float)acc[a][b][m][n][0] * s4.x * swc;
            cp[1 * N_DIM] = (float)acc[a][b][m][n][1] * s4.y * swc;
            cp[2 * N_DIM] = (float)acc[a][b][m][n][2] * s4.z * swc;
            cp[3 * N_DIM] = (float)acc[a][b][m][n][3] * s4.w * swc;
        }
    }
#undef STAGE_A
#undef STAGE_B
#undef LDA
#undef LDB
#undef MMA_Q
#undef MMA_PFA
}

// ---------------------------------------------------------------------------
// Launch: ws usage = 16.7 MB xq + 16.7 MB wq + 32 KB scales.
// ---------------------------------------------------------------------------
extern "C" void kernel_launch(void* const* d_in, const int* in_sizes, int n_in,
                              void* d_out, int out_size, void* d_ws, size_t ws_size,
                              hipStream_t stream) {
    const float* x      = (const float*)d_in[0];
    const int*   packed = (const int*)d_in[1];
    const float* d      = (const float*)d_in[2];
    const float* dmin   = (const float*)d_in[3];
    const int*   scales = (const int*)d_in[4];
    const int*   mins   = (const int*)d_in[5];
    float* out = (float*)d_out;

    int8_t* xq = (int8_t*)d_ws;                               // 16.7 MB
    int8_t* wq = xq + (size_t)M_DIM * K_DIM;                  // 16.7 MB
    float*  sx = (float*)(wq + (size_t)N_DIM * K_DIM);        // 16 KB
    float*  sw = sx + M_DIM;                                  // 16 KB

    quant_x<<<M_DIM, 256, 0, stream>>>(x, xq, sx);
    quant_w<<<N_DIM, 256, 0, stream>>>(packed, d, dmin, scales, mins, wq, sw);
    gemm_i8<<<256, 512, 0, stream>>>(xq, wq, sx, sw, out);
}